// Round 1
// baseline (150.605 us; speedup 1.0000x reference)
//
#include <hip/hip_runtime.h>

#define D 512
#define LOG2E 1.44269504088896340736f

#if defined(__has_builtin)
#if __has_builtin(__builtin_amdgcn_exp2f)
#define EXP2(x) __builtin_amdgcn_exp2f(x)
#else
#define EXP2(x) exp2f(x)
#endif
#else
#define EXP2(x) exp2f(x)
#endif

// Kernel A: per batch row bt, compute attn_out[bt, :].
//   Z[k]    = sum_i exp(b[i] * a[k])
//   c[k]    = a[k] / Z[k]                       (stored in LDS)
//   attn[j] = sum_k c[k] * exp(b[j] * a[k])
// exp(x) computed as exp2(x * log2e); the log2e is folded into the
// per-thread register operand so the inner loop is mul+exp2+fma only.
__global__ __launch_bounds__(256) void attn_kernel(
    const float* __restrict__ a, const float* __restrict__ b,
    float* __restrict__ attn) {
  __shared__ float c_s[D];
  const int bt = blockIdx.x;
  const int tid = threadIdx.x;
  const float* __restrict__ ap = a + (size_t)bt * D;
  const float* __restrict__ bp = b + (size_t)bt * D;

  // ---- pass 1: Z[k] for k = tid, tid+256 ----
#pragma unroll
  for (int kk = 0; kk < 2; ++kk) {
    const int k = tid + kk * 256;
    const float ak_raw = ap[k];          // coalesced vector load
    const float ak = ak_raw * LOG2E;     // fold log2e here
    float z0 = 0.f, z1 = 0.f, z2 = 0.f, z3 = 0.f;
#pragma unroll 4
    for (int i = 0; i < D; i += 4) {
      // bp[i..i+3] are wave-uniform loads -> s_load (scalar cache)
      z0 += EXP2(bp[i + 0] * ak);
      z1 += EXP2(bp[i + 1] * ak);
      z2 += EXP2(bp[i + 2] * ak);
      z3 += EXP2(bp[i + 3] * ak);
    }
    c_s[k] = ak_raw / ((z0 + z1) + (z2 + z3));
  }
  __syncthreads();

  // ---- pass 2: attn[j] for j = tid, tid+256 ----
#pragma unroll
  for (int jj = 0; jj < 2; ++jj) {
    const int j = tid + jj * 256;
    const float bj = bp[j] * LOG2E;      // per-thread, scaled once
    float s0 = 0.f, s1 = 0.f, s2 = 0.f, s3 = 0.f;
#pragma unroll 4
    for (int k = 0; k < D; k += 4) {
      const float4 c4 = *(const float4*)&c_s[k];    // broadcast b128
      // ap[k..k+3] wave-uniform -> s_load
      s0 = fmaf(c4.x, EXP2(ap[k + 0] * bj), s0);
      s1 = fmaf(c4.y, EXP2(ap[k + 1] * bj), s1);
      s2 = fmaf(c4.z, EXP2(ap[k + 2] * bj), s2);
      s3 = fmaf(c4.w, EXP2(ap[k + 3] * bj), s3);
    }
    attn[(size_t)bt * D + j] = (s0 + s1) + (s2 + s3);
  }
}

// Kernel B: out[m, n] = a[m, n] + sum_k attn[m, k] * W[n, k] + bias[n]
// 64x64 output tile, BK=32, 256 threads, 4x4 micro-tile, f32 vector FMA.
// LDS stored transposed ([BK][BM+4]) so the compute phase reads float4
// (ds_read_b128) per operand; +4 pad keeps 16B alignment and rotates banks.
__global__ __launch_bounds__(256) void out_kernel(
    const float* __restrict__ attn, const float* __restrict__ W,
    const float* __restrict__ a, const float* __restrict__ bias,
    float* __restrict__ out) {
  __shared__ float As[32][68];
  __shared__ float Bs[32][68];
  const int tid = threadIdx.x;
  const int bx = blockIdx.x;   // N tile, 0..7
  const int by = blockIdx.y;   // M tile, 0..15
  const int tx = tid & 15;
  const int ty = tid >> 4;
  float acc[4][4] = {};

  for (int k0 = 0; k0 < D; k0 += 32) {
#pragma unroll
    for (int xx = 0; xx < 2; ++xx) {
      const int x = tid + xx * 256;
      const int r = x >> 3;       // 0..63
      const int c4 = x & 7;       // 0..7  (float4 index along k)
      const float4 va =
          *(const float4*)(attn + (size_t)(by * 64 + r) * D + k0 + c4 * 4);
      const float4 vw =
          *(const float4*)(W + (size_t)(bx * 64 + r) * D + k0 + c4 * 4);
      As[c4 * 4 + 0][r] = va.x;
      As[c4 * 4 + 1][r] = va.y;
      As[c4 * 4 + 2][r] = va.z;
      As[c4 * 4 + 3][r] = va.w;
      Bs[c4 * 4 + 0][r] = vw.x;
      Bs[c4 * 4 + 1][r] = vw.y;
      Bs[c4 * 4 + 2][r] = vw.z;
      Bs[c4 * 4 + 3][r] = vw.w;
    }
    __syncthreads();
#pragma unroll
    for (int kk = 0; kk < 32; ++kk) {
      const float4 af = *(const float4*)&As[kk][ty * 4];
      const float4 bf = *(const float4*)&Bs[kk][tx * 4];
      const float afv[4] = {af.x, af.y, af.z, af.w};
      const float bfv[4] = {bf.x, bf.y, bf.z, bf.w};
#pragma unroll
      for (int i = 0; i < 4; ++i)
#pragma unroll
        for (int j = 0; j < 4; ++j) acc[i][j] = fmaf(afv[i], bfv[j], acc[i][j]);
    }
    __syncthreads();
  }

  const int n = bx * 64 + tx * 4;
  const float4 bv = *(const float4*)(bias + n);
#pragma unroll
  for (int i = 0; i < 4; ++i) {
    const int m = by * 64 + ty * 4 + i;
    const float4 av = *(const float4*)(a + (size_t)m * D + n);
    float4 o;
    o.x = av.x + acc[i][0] + bv.x;
    o.y = av.y + acc[i][1] + bv.y;
    o.z = av.z + acc[i][2] + bv.z;
    o.w = av.w + acc[i][3] + bv.w;
    *(float4*)(out + (size_t)m * D + n) = o;
  }
}

extern "C" void kernel_launch(void* const* d_in, const int* in_sizes, int n_in,
                              void* d_out, int out_size, void* d_ws,
                              size_t ws_size, hipStream_t stream) {
  const float* a = (const float*)d_in[0];
  const float* b = (const float*)d_in[1];
  const float* W = (const float*)d_in[2];
  const float* bias = (const float*)d_in[3];
  float* out = (float*)d_out;
  float* attn = (float*)d_ws;  // 1024*512*4 = 2 MB scratch

  attn_kernel<<<1024, 256, 0, stream>>>(a, b, attn);
  out_kernel<<<dim3(8, 16), 256, 0, stream>>>(attn, W, a, bias, out);
}